// Round 1
// 256.459 us; speedup vs baseline: 1.0397x; 1.0397x over previous
//
#include <hip/hip_runtime.h>
#include <math.h>

// Problem constants
#define M_B   128      // batch
#define N_C   1024     // codes
#define K_D   32000    // feature dim (8*250*16)
#define NTILE 64       // codes per block
#define KCHUNK 320     // K per block (16 N-tiles x 100 K-chunks = 1600 blocks)
#define KSTEP 64       // bf16 elems staged in LDS per step (5 steps/block)
#define NSTAGE (KCHUNK / KSTEP)
#define LDSK  (KSTEP + 8)   // +8 bf16 (16B) pad: row stride 144B
#define TOPK  5
#define TEMP  0.1f

typedef short bf16x8 __attribute__((ext_vector_type(8)));  // 8 bf16 (4 VGPRs)
typedef float f32x4  __attribute__((ext_vector_type(4)));

// ws layout (float offsets)
#define WS_CROSS  0         // [128][1024]
#define WS_CNORM  131072    // [1024]
#define WS_LNORM  132096    // [128]
#define WS_TOPI   132224    // [128*5] int
#define WS_TOPW   132864    // [128*5]
#define WS_ZERO_N 132224    // floats to zero (cross+cnorm+lnorm)

// ---------------------------------------------------------------------------
// prep: zero split-K accumulators + copy usage (kernel, not hipMemsetAsync —
// capture-safe; merged to save one launch).
// ---------------------------------------------------------------------------
__global__ void prep(float* __restrict__ ws, const float* __restrict__ usage_in,
                     float* __restrict__ usage_out) {
  const int i = blockIdx.x * 256 + threadIdx.x;
  if (i < WS_ZERO_N) ws[i] = 0.f;
  if (i < N_C) usage_out[i] = usage_in[i];
}

// fp32x8 -> bf16x8 hi plane + lo plane (exact split: x = hi + lo + ~2^-18 rel)
__device__ inline void cvt8(const float4 p0, const float4 p1, uint4& hi,
                            uint4& lo) {
  const unsigned int u0 = __float_as_uint(p0.x), u1 = __float_as_uint(p0.y);
  const unsigned int u2 = __float_as_uint(p0.z), u3 = __float_as_uint(p0.w);
  const unsigned int u4 = __float_as_uint(p1.x), u5 = __float_as_uint(p1.y);
  const unsigned int u6 = __float_as_uint(p1.z), u7 = __float_as_uint(p1.w);
  hi.x = (u0 >> 16) | (u1 & 0xFFFF0000u);
  hi.y = (u2 >> 16) | (u3 & 0xFFFF0000u);
  hi.z = (u4 >> 16) | (u5 & 0xFFFF0000u);
  hi.w = (u6 >> 16) | (u7 & 0xFFFF0000u);
  const float l0 = p0.x - __uint_as_float(u0 & 0xFFFF0000u);
  const float l1 = p0.y - __uint_as_float(u1 & 0xFFFF0000u);
  const float l2 = p0.z - __uint_as_float(u2 & 0xFFFF0000u);
  const float l3 = p0.w - __uint_as_float(u3 & 0xFFFF0000u);
  const float l4 = p1.x - __uint_as_float(u4 & 0xFFFF0000u);
  const float l5 = p1.y - __uint_as_float(u5 & 0xFFFF0000u);
  const float l6 = p1.z - __uint_as_float(u6 & 0xFFFF0000u);
  const float l7 = p1.w - __uint_as_float(u7 & 0xFFFF0000u);
  lo.x = (__float_as_uint(l0) >> 16) | (__float_as_uint(l1) & 0xFFFF0000u);
  lo.y = (__float_as_uint(l2) >> 16) | (__float_as_uint(l3) & 0xFFFF0000u);
  lo.z = (__float_as_uint(l4) >> 16) | (__float_as_uint(l5) & 0xFFFF0000u);
  lo.w = (__float_as_uint(l6) >> 16) | (__float_as_uint(l7) & 0xFFFF0000u);
}

__device__ inline float sq8(const float4 p0, const float4 p1) {
  return p0.x * p0.x + p0.y * p0.y + p0.z * p0.z + p0.w * p0.w +
         p1.x * p1.x + p1.y * p1.y + p1.z * p1.z + p1.w * p1.w;
}

// ---------------------------------------------------------------------------
// Split-bf16 MFMA distance GEMM, double-buffered + software-pipelined:
//   per step: issue A loads (oldest), issue NEXT B loads, barrier,
//             cvt A + MFMA on current LDS buffer (B loads in flight across
//             the MFMAs -> compiler emits vmcnt(8)/vmcnt(4)/vmcnt(0) chain),
//             then cvt B + write other buffer.  One barrier per step.
// LDS 36.9 KB/block -> 4 blocks/CU; grid 1600 blocks (6.25/CU) feeds it.
// ---------------------------------------------------------------------------
__global__ __launch_bounds__(256, 4) void gemm_dist(
    const float* __restrict__ latent, const float* __restrict__ codebook,
    float* __restrict__ cross, float* __restrict__ cnorm,
    float* __restrict__ lnorm) {
  __shared__ alignas(16) unsigned short Bh[2][NTILE][LDSK];
  __shared__ alignas(16) unsigned short Bl[2][NTILE][LDSK];

  const int tid  = threadIdx.x;
  const int nt   = blockIdx.x;   // 0..15 N tile
  const int kc   = blockIdx.y;   // 0..99 K chunk
  const int wave = tid >> 6;     // 0..3: M rows [32w, 32w+32)
  const int lane = tid & 63;
  const int lrow = lane & 15;    // MFMA fragment row/col index
  const int quad = lane >> 4;    // MFMA k-quad

  const int brow = tid >> 2;        // staging: B row 0..63
  const int bcol = (tid & 3) * 16;  // 16 k-elems (2 float4) per thread

  f32x4 acc[2][4];
#pragma unroll
  for (int mt = 0; mt < 2; ++mt)
#pragma unroll
    for (int n = 0; n < 4; ++n) {
      acc[mt][n][0] = 0.f; acc[mt][n][1] = 0.f;
      acc[mt][n][2] = 0.f; acc[mt][n][3] = 0.f;
    }
  float lsq[2] = {0.f, 0.f};
  float csq = 0.f;

  const int kbase = kc * KCHUNK;
  const float* browp = codebook + (size_t)(nt * NTILE + brow) * K_D;

  // ---- prologue: stage step 0 into buffer 0 ----
#pragma unroll
  for (int u = 0; u < 2; ++u) {
    const int kk = kbase + bcol + u * 8;
    const float4 p0 = *reinterpret_cast<const float4*>(browp + kk);
    const float4 p1 = *reinterpret_cast<const float4*>(browp + kk + 4);
    uint4 hi, lo;
    cvt8(p0, p1, hi, lo);
    *reinterpret_cast<uint4*>(&Bh[0][brow][bcol + u * 8]) = hi;
    *reinterpret_cast<uint4*>(&Bl[0][brow][bcol + u * 8]) = lo;
    csq += sq8(p0, p1);
  }

  int cur = 0;
  for (int s = 0; s < NSTAGE; ++s) {
    const int k0 = kbase + s * KSTEP;
    // ---- issue A loads for this step (oldest in vmcnt queue) ----
    float4 ap[2][2][2];  // [kh][mt][p0/p1]
#pragma unroll
    for (int kh = 0; kh < 2; ++kh)
#pragma unroll
      for (int mt = 0; mt < 2; ++mt) {
        const float* ar = latent +
                          (size_t)(wave * 32 + mt * 16 + lrow) * K_D + k0 +
                          kh * 32 + quad * 8;
        ap[kh][mt][0] = *reinterpret_cast<const float4*>(ar);
        ap[kh][mt][1] = *reinterpret_cast<const float4*>(ar + 4);
      }
    // ---- issue NEXT step's B loads (stay in flight across the MFMAs) ----
    float4 bp[2][2];
    if (s + 1 < NSTAGE) {
      const int kn = kbase + (s + 1) * KSTEP + bcol;
#pragma unroll
      for (int u = 0; u < 2; ++u) {
        bp[u][0] = *reinterpret_cast<const float4*>(browp + kn + u * 8);
        bp[u][1] = *reinterpret_cast<const float4*>(browp + kn + u * 8 + 4);
      }
    }
    __syncthreads();  // buf[cur] writes (prev step) visible; prev reads done
    // ---- compute: per kh, cvt A then MFMA from buf[cur] ----
#pragma unroll
    for (int kh = 0; kh < 2; ++kh) {
      bf16x8 ah[2], al[2];
#pragma unroll
      for (int mt = 0; mt < 2; ++mt) {
        uint4 hi, lo;
        cvt8(ap[kh][mt][0], ap[kh][mt][1], hi, lo);
        ah[mt] = *reinterpret_cast<bf16x8*>(&hi);
        al[mt] = *reinterpret_cast<bf16x8*>(&lo);
        if (nt == 0) lsq[mt] += sq8(ap[kh][mt][0], ap[kh][mt][1]);
      }
      const int kf = kh * 32 + quad * 8;
#pragma unroll
      for (int n = 0; n < 4; ++n) {
        const bf16x8 bh =
            *reinterpret_cast<const bf16x8*>(&Bh[cur][n * 16 + lrow][kf]);
        const bf16x8 bl =
            *reinterpret_cast<const bf16x8*>(&Bl[cur][n * 16 + lrow][kf]);
#pragma unroll
        for (int mt = 0; mt < 2; ++mt) {
          acc[mt][n] = __builtin_amdgcn_mfma_f32_16x16x32_bf16(
              ah[mt], bh, acc[mt][n], 0, 0, 0);
          acc[mt][n] = __builtin_amdgcn_mfma_f32_16x16x32_bf16(
              ah[mt], bl, acc[mt][n], 0, 0, 0);
          acc[mt][n] = __builtin_amdgcn_mfma_f32_16x16x32_bf16(
              al[mt], bh, acc[mt][n], 0, 0, 0);
        }
      }
    }
    // ---- cvt + write next B buffer (waits vmcnt(0) here, after MFMAs) ----
    if (s + 1 < NSTAGE) {
      const int nxt = cur ^ 1;
#pragma unroll
      for (int u = 0; u < 2; ++u) {
        uint4 hi, lo;
        cvt8(bp[u][0], bp[u][1], hi, lo);
        *reinterpret_cast<uint4*>(&Bh[nxt][brow][bcol + u * 8]) = hi;
        *reinterpret_cast<uint4*>(&Bl[nxt][brow][bcol + u * 8]) = lo;
        csq += sq8(bp[u][0], bp[u][1]);
      }
    }
    cur ^= 1;
  }

  // ---- split-K accumulate: C/D layout col=lane&15, row=quad*4+reg (m89) ----
#pragma unroll
  for (int mt = 0; mt < 2; ++mt) {
    const int mrow0 = wave * 32 + mt * 16 + quad * 4;
#pragma unroll
    for (int n = 0; n < 4; ++n) {
      const int col = nt * NTILE + n * 16 + lrow;
#pragma unroll
      for (int r = 0; r < 4; ++r)
        atomicAdd(cross + (size_t)(mrow0 + r) * N_C + col, acc[mt][n][r]);
    }
  }

  // ---- codebook norms: 4 threads (tid&3) share row brow ----
  csq += __shfl_down(csq, 2, 4);
  csq += __shfl_down(csq, 1, 4);
  if ((tid & 3) == 0) atomicAdd(cnorm + nt * NTILE + brow, csq);
  // ---- latent norms (nt==0 blocks cover all K): reduce over quads ----
  if (nt == 0) {
#pragma unroll
    for (int mt = 0; mt < 2; ++mt) {
      lsq[mt] += __shfl_down(lsq[mt], 32);
      lsq[mt] += __shfl_down(lsq[mt], 16);
      if (lane < 16) atomicAdd(lnorm + wave * 32 + mt * 16 + lane, lsq[mt]);
    }
  }
}

// ---------------------------------------------------------------------------
// Per-latent finalize: d2 -> top-5 (lowest-index tie-break) -> softmax ->
// outputs + usage scatter + ws stash for the quantize gather.
// ---------------------------------------------------------------------------
__global__ __launch_bounds__(256) void finalize(
    const float* __restrict__ cross, const float* __restrict__ cnorm,
    const float* __restrict__ lnorm, float* __restrict__ out_idx,
    float* __restrict__ out_dist, float* __restrict__ out_usage,
    int* __restrict__ topidx, float* __restrict__ topw) {
  const int b = blockIdx.x;
  const int tid = threadIdx.x;
  __shared__ float rv[256];
  __shared__ int ri[256];
  __shared__ float seld[TOPK];
  __shared__ int selj[TOPK];

  float d[4];
  bool used[4];
  const float ln = lnorm[b];
#pragma unroll
  for (int i = 0; i < 4; i++) {
    const int j = i * 256 + tid;
    d[i] = ln + cnorm[j] - 2.f * cross[b * N_C + j];
    used[i] = false;
  }
  for (int it = 0; it < TOPK; ++it) {
    float best = 3.4e38f;
    int bj = N_C;
#pragma unroll
    for (int i = 0; i < 4; i++) {  // ascending j + strict < => lowest idx wins
      const int j = i * 256 + tid;
      if (!used[i] && d[i] < best) { best = d[i]; bj = j; }
    }
    rv[tid] = best;
    ri[tid] = bj;
    __syncthreads();
    for (int off = 128; off > 0; off >>= 1) {
      if (tid < off) {
        const float ov = rv[tid + off];
        const int oj = ri[tid + off];
        if (ov < rv[tid] || (ov == rv[tid] && oj < ri[tid])) {
          rv[tid] = ov;
          ri[tid] = oj;
        }
      }
      __syncthreads();
    }
    const int jw = ri[0];
    const float dw = rv[0];
    if (tid == 0) { selj[it] = jw; seld[it] = dw; }
    if ((jw & 255) == tid) used[jw >> 8] = true;  // exclude winner
    __syncthreads();
  }
  if (tid == 0) {
    float dist[TOPK], w[TOPK], wsum = 0.f;
#pragma unroll
    for (int k = 0; k < TOPK; k++) dist[k] = sqrtf(fmaxf(seld[k], 0.f));
#pragma unroll
    for (int k = 0; k < TOPK; k++) {
      w[k] = expf((dist[0] - dist[k]) / TEMP);  // stable: dist[0] is min
      wsum += w[k];
    }
#pragma unroll
    for (int k = 0; k < TOPK; k++) {
      w[k] /= wsum;
      topidx[b * TOPK + k] = selj[k];
      topw[b * TOPK + k] = w[k];
      atomicAdd(out_usage + selj[k], w[k]);
    }
    out_idx[b] = (float)selj[0];  // harness reads flat float32 buffer
    out_dist[b] = dist[0];
  }
}

// ---------------------------------------------------------------------------
// quantized[b,:] = sum_k w[b,k] * codebook[idx[b,k],:]   (float4 gather)
// ---------------------------------------------------------------------------
__global__ __launch_bounds__(256) void quantize(
    const float* __restrict__ codebook, const int* __restrict__ topidx,
    const float* __restrict__ topw, float* __restrict__ out) {
  const int b = blockIdx.y;
  const int dc = blockIdx.x;  // 8 chunks of 1000 float4 = 32000 floats
  const int tid = threadIdx.x;
  int idx[TOPK];
  float w[TOPK];
#pragma unroll
  for (int k = 0; k < TOPK; k++) {
    idx[k] = topidx[b * TOPK + k];
    w[k] = topw[b * TOPK + k];
  }
  const int f4base = dc * 1000;
#pragma unroll
  for (int s = 0; s < 4; s++) {
    const int f = tid + s * 256;
    if (f < 1000) {
      const int dpos = (f4base + f) * 4;
      float4 q = {0.f, 0.f, 0.f, 0.f};
#pragma unroll
      for (int k = 0; k < TOPK; k++) {
        const float4 c = *reinterpret_cast<const float4*>(
            codebook + (size_t)idx[k] * K_D + dpos);
        q.x += w[k] * c.x;
        q.y += w[k] * c.y;
        q.z += w[k] * c.z;
        q.w += w[k] * c.w;
      }
      *reinterpret_cast<float4*>(out + (size_t)b * K_D + dpos) = q;
    }
  }
}

// ---------------------------------------------------------------------------
extern "C" void kernel_launch(void* const* d_in, const int* in_sizes, int n_in,
                              void* d_out, int out_size, void* d_ws,
                              size_t ws_size, hipStream_t stream) {
  const float* latent = (const float*)d_in[0];    // 128*32000
  const float* codebook = (const float*)d_in[1];  // 1024*32000
  const float* usage_in = (const float*)d_in[2];  // 1024

  float* out = (float*)d_out;
  float* quant = out;                // 4,096,000
  float* out_idx = out + 4096000;    // 128
  float* out_dist = out + 4096128;   // 128
  float* out_usage = out + 4096256;  // 1024

  float* ws = (float*)d_ws;
  float* cross = ws + WS_CROSS;
  float* cnorm = ws + WS_CNORM;
  float* lnorm = ws + WS_LNORM;
  int* topidx = (int*)(ws + WS_TOPI);
  float* topw = ws + WS_TOPW;

  prep<<<(WS_ZERO_N + 255) / 256, 256, 0, stream>>>(ws, usage_in, out_usage);
  gemm_dist<<<dim3(16, 100), 256, 0, stream>>>(latent, codebook, cross, cnorm,
                                               lnorm);
  finalize<<<128, 256, 0, stream>>>(cross, cnorm, lnorm, out_idx, out_dist,
                                    out_usage, topidx, topw);
  quantize<<<dim3(8, 128), 256, 0, stream>>>(codebook, topidx, topw, quant);
}